// Round 3
// baseline (1888.926 us; speedup 1.0000x reference)
//
#include <hip/hip_runtime.h>
#include <hip/hip_bf16.h>

#define N_ROWS 8192
#define K_CODES 8192
#define D_DIM 512
#define KC_SPLIT 384  // OpenBLAS SGEMM kc panel (Haswell/Zen: 384)

// ---------------------------------------------------------------------------
// numpy pairwise summation of squares, bit-exact emulation.
// temp = fl32(v*v) elementwise, then np.sum pairwise:
//   n=512 -> pw(0:256)+pw(256:512); 256 -> base128+base128
//   base128: r[j]=t[j] (j<8); for i=8..120 step 8: r[j]+=t[i+j];
//            res = ((r0+r1)+(r2+r3))+((r4+r5)+(r6+r7))
// All ops via _rn intrinsics: no FMA contraction, no reassociation.
// ---------------------------------------------------------------------------
__device__ __forceinline__ float pw_base128_sq(const float* __restrict__ p) {
  float r0 = __fmul_rn(p[0], p[0]);
  float r1 = __fmul_rn(p[1], p[1]);
  float r2 = __fmul_rn(p[2], p[2]);
  float r3 = __fmul_rn(p[3], p[3]);
  float r4 = __fmul_rn(p[4], p[4]);
  float r5 = __fmul_rn(p[5], p[5]);
  float r6 = __fmul_rn(p[6], p[6]);
  float r7 = __fmul_rn(p[7], p[7]);
  for (int i = 8; i < 128; i += 8) {
    r0 = __fadd_rn(r0, __fmul_rn(p[i + 0], p[i + 0]));
    r1 = __fadd_rn(r1, __fmul_rn(p[i + 1], p[i + 1]));
    r2 = __fadd_rn(r2, __fmul_rn(p[i + 2], p[i + 2]));
    r3 = __fadd_rn(r3, __fmul_rn(p[i + 3], p[i + 3]));
    r4 = __fadd_rn(r4, __fmul_rn(p[i + 4], p[i + 4]));
    r5 = __fadd_rn(r5, __fmul_rn(p[i + 5], p[i + 5]));
    r6 = __fadd_rn(r6, __fmul_rn(p[i + 6], p[i + 6]));
    r7 = __fadd_rn(r7, __fmul_rn(p[i + 7], p[i + 7]));
  }
  return __fadd_rn(__fadd_rn(__fadd_rn(r0, r1), __fadd_rn(r2, r3)),
                   __fadd_rn(__fadd_rn(r4, r5), __fadd_rn(r6, r7)));
}

__device__ __forceinline__ float pw_sq_512(const float* __restrict__ p) {
  float b0 = pw_base128_sq(p);
  float b1 = pw_base128_sq(p + 128);
  float b2 = pw_base128_sq(p + 256);
  float b3 = pw_base128_sq(p + 384);
  return __fadd_rn(__fadd_rn(b0, b1), __fadd_rn(b2, b3));
}

// ---------------------------------------------------------------------------
// Kernel 1: x_sq32[n] and e_sq32[k] with numpy-pairwise f32 semantics.
// ---------------------------------------------------------------------------
__global__ __launch_bounds__(256) void vq_sq(const float* __restrict__ x,
                                             const float* __restrict__ emb,
                                             float* __restrict__ x_sq,
                                             float* __restrict__ e_sq) {
  const int tid = blockIdx.x * 256 + threadIdx.x;
  if (tid < N_ROWS) {
    x_sq[tid] = pw_sq_512(x + tid * D_DIM);
  } else {
    const int k = tid - N_ROWS;
    e_sq[k] = pw_sq_512(emb + k * D_DIM);
  }
}

// ---------------------------------------------------------------------------
// Kernel 2: tiled f32 distance + argmin, emulating the f32 reference:
//   dot32 = f32 FMA chain d=0..383 (+) f32 FMA chain d=384..511  (sgemm kc)
//   dist  = fl32( fl32(x_sq32 - 2*dot32) + e_sq32 )
// Key = (sortable_f32_bits << 32) | k ; u64 atomicMin -> min dist, then min k
// (== np.argmin first-occurrence tie-break on the f32 grid).
// ---------------------------------------------------------------------------
__global__ __launch_bounds__(256) void vq_dist(const float* __restrict__ x,
                                               const float* __restrict__ emb,
                                               const float* __restrict__ x_sq,
                                               const float* __restrict__ e_sq,
                                               unsigned long long* __restrict__ slots) {
  __shared__ float xs[64][33];
  __shared__ float es[64][33];
  __shared__ unsigned long long rowmin[64];

  const int t = threadIdx.x;
  const int n0 = blockIdx.y * 64;
  const int k0 = blockIdx.x * 64;

  float acc_a[4][4], acc_b[4][4];
#pragma unroll
  for (int i = 0; i < 4; ++i)
#pragma unroll
    for (int j = 0; j < 4; ++j) { acc_a[i][j] = 0.0f; acc_b[i][j] = 0.0f; }

  if (t < 64) rowmin[t] = ~0ULL;

  const int tn = (t >> 4) << 2;
  const int tk = (t & 15) << 2;

  // Phase A: d in [0, 384)
  for (int d0 = 0; d0 < KC_SPLIT; d0 += 32) {
    __syncthreads();
#pragma unroll
    for (int i = 0; i < 8; ++i) {
      int idx = t + i * 256;
      int r = idx >> 5;
      int c = idx & 31;
      xs[r][c] = x[(n0 + r) * D_DIM + d0 + c];
      es[r][c] = emb[(k0 + r) * D_DIM + d0 + c];
    }
    __syncthreads();
    for (int dd = 0; dd < 32; ++dd) {
      float a0 = xs[tn + 0][dd], a1 = xs[tn + 1][dd];
      float a2 = xs[tn + 2][dd], a3 = xs[tn + 3][dd];
      float b0 = es[tk + 0][dd], b1 = es[tk + 1][dd];
      float b2 = es[tk + 2][dd], b3 = es[tk + 3][dd];
      acc_a[0][0] = __fmaf_rn(a0, b0, acc_a[0][0]);
      acc_a[0][1] = __fmaf_rn(a0, b1, acc_a[0][1]);
      acc_a[0][2] = __fmaf_rn(a0, b2, acc_a[0][2]);
      acc_a[0][3] = __fmaf_rn(a0, b3, acc_a[0][3]);
      acc_a[1][0] = __fmaf_rn(a1, b0, acc_a[1][0]);
      acc_a[1][1] = __fmaf_rn(a1, b1, acc_a[1][1]);
      acc_a[1][2] = __fmaf_rn(a1, b2, acc_a[1][2]);
      acc_a[1][3] = __fmaf_rn(a1, b3, acc_a[1][3]);
      acc_a[2][0] = __fmaf_rn(a2, b0, acc_a[2][0]);
      acc_a[2][1] = __fmaf_rn(a2, b1, acc_a[2][1]);
      acc_a[2][2] = __fmaf_rn(a2, b2, acc_a[2][2]);
      acc_a[2][3] = __fmaf_rn(a2, b3, acc_a[2][3]);
      acc_a[3][0] = __fmaf_rn(a3, b0, acc_a[3][0]);
      acc_a[3][1] = __fmaf_rn(a3, b1, acc_a[3][1]);
      acc_a[3][2] = __fmaf_rn(a3, b2, acc_a[3][2]);
      acc_a[3][3] = __fmaf_rn(a3, b3, acc_a[3][3]);
    }
  }
  // Phase B: d in [384, 512)
  for (int d0 = KC_SPLIT; d0 < D_DIM; d0 += 32) {
    __syncthreads();
#pragma unroll
    for (int i = 0; i < 8; ++i) {
      int idx = t + i * 256;
      int r = idx >> 5;
      int c = idx & 31;
      xs[r][c] = x[(n0 + r) * D_DIM + d0 + c];
      es[r][c] = emb[(k0 + r) * D_DIM + d0 + c];
    }
    __syncthreads();
    for (int dd = 0; dd < 32; ++dd) {
      float a0 = xs[tn + 0][dd], a1 = xs[tn + 1][dd];
      float a2 = xs[tn + 2][dd], a3 = xs[tn + 3][dd];
      float b0 = es[tk + 0][dd], b1 = es[tk + 1][dd];
      float b2 = es[tk + 2][dd], b3 = es[tk + 3][dd];
      acc_b[0][0] = __fmaf_rn(a0, b0, acc_b[0][0]);
      acc_b[0][1] = __fmaf_rn(a0, b1, acc_b[0][1]);
      acc_b[0][2] = __fmaf_rn(a0, b2, acc_b[0][2]);
      acc_b[0][3] = __fmaf_rn(a0, b3, acc_b[0][3]);
      acc_b[1][0] = __fmaf_rn(a1, b0, acc_b[1][0]);
      acc_b[1][1] = __fmaf_rn(a1, b1, acc_b[1][1]);
      acc_b[1][2] = __fmaf_rn(a1, b2, acc_b[1][2]);
      acc_b[1][3] = __fmaf_rn(a1, b3, acc_b[1][3]);
      acc_b[2][0] = __fmaf_rn(a2, b0, acc_b[2][0]);
      acc_b[2][1] = __fmaf_rn(a2, b1, acc_b[2][1]);
      acc_b[2][2] = __fmaf_rn(a2, b2, acc_b[2][2]);
      acc_b[2][3] = __fmaf_rn(a2, b3, acc_b[2][3]);
      acc_b[3][0] = __fmaf_rn(a3, b0, acc_b[3][0]);
      acc_b[3][1] = __fmaf_rn(a3, b1, acc_b[3][1]);
      acc_b[3][2] = __fmaf_rn(a3, b2, acc_b[3][2]);
      acc_b[3][3] = __fmaf_rn(a3, b3, acc_b[3][3]);
    }
  }

#pragma unroll
  for (int i = 0; i < 4; ++i) {
    const float xsqv = x_sq[n0 + tn + i];
    unsigned long long best = ~0ULL;
#pragma unroll
    for (int j = 0; j < 4; ++j) {
      const int kg = k0 + tk + j;
      float dot = __fadd_rn(acc_a[i][j], acc_b[i][j]);
      float t1 = __fsub_rn(xsqv, __fmul_rn(2.0f, dot));
      float dist = __fadd_rn(t1, e_sq[kg]);
      unsigned int b = __float_as_uint(dist);
      unsigned int s = (b & 0x80000000u) ? ~b : (b | 0x80000000u);
      unsigned long long key =
          ((unsigned long long)s << 32) | (unsigned int)kg;
      best = best < key ? best : key;
    }
    atomicMin(&rowmin[tn + i], best);
  }
  __syncthreads();
  if (t < 64) atomicMin(&slots[n0 + t], rowmin[t]);
}

// ---------------------------------------------------------------------------
// Kernel 3: gather quantized rows (f32 passthrough), indices, loss sum.
// ---------------------------------------------------------------------------
__global__ __launch_bounds__(256) void vq_out(const float* __restrict__ x,
                                              const float* __restrict__ emb,
                                              const unsigned long long* __restrict__ slots,
                                              float* __restrict__ out_q,
                                              float* __restrict__ out_idx,
                                              double* __restrict__ loss_acc) {
  const int n = blockIdx.x;
  const int t = threadIdx.x;
  const int idx = (int)(slots[n] & 0xFFFFFFFFULL);
  const float* xr = x + n * D_DIM;
  const float* qr = emb + idx * D_DIM;
  double s = 0.0;
  for (int d = t; d < D_DIM; d += 256) {
    float q = qr[d];
    float xv = xr[d];
    double diff = (double)xv - (double)q;
    s = fma(diff, diff, s);
    out_q[n * D_DIM + d] = q;
  }
  for (int off = 32; off > 0; off >>= 1) s += __shfl_down(s, off, 64);
  __shared__ double part[4];
  if ((t & 63) == 0) part[t >> 6] = s;
  __syncthreads();
  if (t == 0) {
    double tot = (part[0] + part[1]) + (part[2] + part[3]);
    atomicAdd(loss_acc, tot);
    out_idx[n] = (float)idx;
  }
}

__global__ void vq_loss(const double* __restrict__ loss_acc,
                        float* __restrict__ out_s) {
  double m = *loss_acc / (double)(N_ROWS * D_DIM);
  out_s[0] = (float)(0.25 * m);
  out_s[1] = (float)m;
  out_s[2] = (float)(1.25 * m);
}

extern "C" void kernel_launch(void* const* d_in, const int* in_sizes, int n_in,
                              void* d_out, int out_size, void* d_ws, size_t ws_size,
                              hipStream_t stream) {
  const float* x = (const float*)d_in[0];
  const float* emb = (const float*)d_in[1];
  float* out = (float*)d_out;

  // ws: [0,64K) u64 slots; [64K,96K) f32 x_sq; [96K,128K) f32 e_sq; [128K] f64 loss
  unsigned long long* slots = (unsigned long long*)d_ws;
  float* x_sq = (float*)((char*)d_ws + 65536);
  float* e_sq = (float*)((char*)d_ws + 98304);
  double* loss_acc = (double*)((char*)d_ws + 131072);

  hipMemsetAsync(d_ws, 0xFF, N_ROWS * sizeof(unsigned long long), stream);
  hipMemsetAsync(loss_acc, 0, sizeof(double), stream);

  vq_sq<<<(2 * N_ROWS) / 256, 256, 0, stream>>>(x, emb, x_sq, e_sq);

  dim3 grid(K_CODES / 64, N_ROWS / 64);
  vq_dist<<<grid, 256, 0, stream>>>(x, emb, x_sq, e_sq, slots);

  vq_out<<<N_ROWS, 256, 0, stream>>>(x, emb, slots, out, out + N_ROWS * D_DIM,
                                     loss_acc);
  vq_loss<<<1, 1, 0, stream>>>(loss_acc, out + N_ROWS * D_DIM + N_ROWS);
}

// Round 4
// 1178.735 us; speedup vs baseline: 1.6025x; 1.6025x over previous
//
#include <hip/hip_runtime.h>

#define N_ROWS 8192
#define K_CODES 8192
#define D_DIM 512

typedef unsigned long long u64;

// ---------------------------------------------------------------------------
// numpy pairwise summation of squares (bit-exact, unchanged from passing R3).
// ---------------------------------------------------------------------------
__device__ __forceinline__ float pw_base128_sq(const float* __restrict__ p) {
  float r0 = __fmul_rn(p[0], p[0]);
  float r1 = __fmul_rn(p[1], p[1]);
  float r2 = __fmul_rn(p[2], p[2]);
  float r3 = __fmul_rn(p[3], p[3]);
  float r4 = __fmul_rn(p[4], p[4]);
  float r5 = __fmul_rn(p[5], p[5]);
  float r6 = __fmul_rn(p[6], p[6]);
  float r7 = __fmul_rn(p[7], p[7]);
  for (int i = 8; i < 128; i += 8) {
    r0 = __fadd_rn(r0, __fmul_rn(p[i + 0], p[i + 0]));
    r1 = __fadd_rn(r1, __fmul_rn(p[i + 1], p[i + 1]));
    r2 = __fadd_rn(r2, __fmul_rn(p[i + 2], p[i + 2]));
    r3 = __fadd_rn(r3, __fmul_rn(p[i + 3], p[i + 3]));
    r4 = __fadd_rn(r4, __fmul_rn(p[i + 4], p[i + 4]));
    r5 = __fadd_rn(r5, __fmul_rn(p[i + 5], p[i + 5]));
    r6 = __fadd_rn(r6, __fmul_rn(p[i + 6], p[i + 6]));
    r7 = __fadd_rn(r7, __fmul_rn(p[i + 7], p[i + 7]));
  }
  return __fadd_rn(__fadd_rn(__fadd_rn(r0, r1), __fadd_rn(r2, r3)),
                   __fadd_rn(__fadd_rn(r4, r5), __fadd_rn(r6, r7)));
}

__device__ __forceinline__ float pw_sq_512(const float* __restrict__ p) {
  float b0 = pw_base128_sq(p);
  float b1 = pw_base128_sq(p + 128);
  float b2 = pw_base128_sq(p + 256);
  float b3 = pw_base128_sq(p + 384);
  return __fadd_rn(__fadd_rn(b0, b1), __fadd_rn(b2, b3));
}

__global__ __launch_bounds__(256) void vq_sq(const float* __restrict__ x,
                                             const float* __restrict__ emb,
                                             float* __restrict__ x_sq,
                                             float* __restrict__ e_sq) {
  const int tid = blockIdx.x * 256 + threadIdx.x;
  if (tid < N_ROWS) {
    x_sq[tid] = pw_sq_512(x + tid * D_DIM);
  } else {
    const int k = tid - N_ROWS;
    e_sq[k] = pw_sq_512(emb + k * D_DIM);
  }
}

// ---------------------------------------------------------------------------
// Kernel 2: distance + argmin. Tile 32n x 256k per block (4 waves).
// - wave owns 8 n-rows exclusively -> x via SGPR s_load (readfirstlane base)
// - e-tile (256k x 32dd) in LDS, quad-XOR swizzled, staged by global_load_lds
//   with pre-swizzled global source (linear LDS dest)
// - thread micro-tile 8n x 4k, acc split accA (d<384) / accB (d>=384);
//   FMA chain identical to the R3-passing kernel (ascending dd, _rn ops).
// ---------------------------------------------------------------------------
__global__ __launch_bounds__(256, 4) void vq_dist(
    const float* __restrict__ x, const float* __restrict__ e,
    const float* __restrict__ x_sq, const float* __restrict__ e_sq,
    u64* __restrict__ slots) {
  __shared__ float es_lds[256 * 32];  // 32 KB

  const int t = threadIdx.x;
  const int lane = t & 63;

  // XCD-aware bijective swizzle (8192 blocks = 1024 per XCD):
  // consecutive swz on one XCD share the same k-panel -> L2 reuse.
  const int bx = blockIdx.x;
  const int swz = (bx & 7) * 1024 + (bx >> 3);
  const int kb = swz >> 8;   // 0..31
  const int nb = swz & 255;  // 0..255
  const int k0 = kb * 256;
  const int n0w = __builtin_amdgcn_readfirstlane(nb * 32 + (t >> 6) * 8);

  const float* xw = x + (size_t)n0w * D_DIM;  // wave-uniform row base

  // Stage-address precompute: lane-linear LDS dest, inverse-swizzled source.
  // Linear float offset F = 4*(t+256i): row=(F>>5), phys quad=(F>>2)&7.
  int srow[8], sq4[8], soff[8];
#pragma unroll
  for (int i = 0; i < 8; ++i) {
    srow[i] = (t >> 3) + 32 * i;
    sq4[i] = 4 * ((t & 7) ^ (((t >> 6) + 4 * i) & 7));
    soff[i] = 4 * (t + 256 * i);
  }

  float accA[8][4], accB[8][4];
#pragma unroll
  for (int r = 0; r < 8; ++r)
#pragma unroll
    for (int j = 0; j < 4; ++j) { accA[r][j] = 0.0f; accB[r][j] = 0.0f; }

  auto stage = [&](int dd0) {
#pragma unroll
    for (int i = 0; i < 8; ++i) {
      const float* g = e + (size_t)(k0 + srow[i]) * D_DIM + dd0 + sq4[i];
      __builtin_amdgcn_global_load_lds(
          (const __attribute__((address_space(1))) void*)g,
          (__attribute__((address_space(3))) void*)(es_lds + soff[i]), 16, 0, 0);
    }
  };

  auto compute = [&](int dd0, float (&acc)[8][4]) {
#pragma unroll
    for (int g = 0; g < 8; ++g) {
      float4 ev[4];
#pragma unroll
      for (int j = 0; j < 4; ++j) {
        const int kloc = lane * 4 + j;
        const int q = g ^ ((kloc >> 3) & 7);
        ev[j] = *reinterpret_cast<const float4*>(&es_lds[kloc * 32 + 4 * q]);
      }
      const int dd = dd0 + 4 * g;
#pragma unroll
      for (int r = 0; r < 8; ++r) {
        const float4 xv = *reinterpret_cast<const float4*>(xw + r * D_DIM + dd);
#pragma unroll
        for (int j = 0; j < 4; ++j) {
          float a = acc[r][j];
          a = __fmaf_rn(xv.x, ev[j].x, a);
          a = __fmaf_rn(xv.y, ev[j].y, a);
          a = __fmaf_rn(xv.z, ev[j].z, a);
          a = __fmaf_rn(xv.w, ev[j].w, a);
          acc[r][j] = a;
        }
      }
    }
  };

  for (int c = 0; c < 12; ++c) {  // phase A: d in [0,384)
    __syncthreads();
    stage(c * 32);
    asm volatile("s_waitcnt vmcnt(0)" ::: "memory");
    __syncthreads();
    compute(c * 32, accA);
  }
  for (int c = 12; c < 16; ++c) {  // phase B: d in [384,512)
    __syncthreads();
    stage(c * 32);
    asm volatile("s_waitcnt vmcnt(0)" ::: "memory");
    __syncthreads();
    compute(c * 32, accB);
  }

  // Epilogue: dist = fl(fl(x_sq - 2*dot) + e_sq); key-packed argmin.
  const float4 xsqa = *reinterpret_cast<const float4*>(x_sq + n0w);
  const float4 xsqb = *reinterpret_cast<const float4*>(x_sq + n0w + 4);
  const float xsq[8] = {xsqa.x, xsqa.y, xsqa.z, xsqa.w,
                        xsqb.x, xsqb.y, xsqb.z, xsqb.w};
  const int klane = k0 + lane * 4;
  const float4 esq = *reinterpret_cast<const float4*>(e_sq + klane);
  const float esqv[4] = {esq.x, esq.y, esq.z, esq.w};

#pragma unroll
  for (int r = 0; r < 8; ++r) {
    u64 best = ~0ULL;
#pragma unroll
    for (int j = 0; j < 4; ++j) {
      float dot = __fadd_rn(accA[r][j], accB[r][j]);
      float dist = __fadd_rn(__fsub_rn(xsq[r], __fmul_rn(2.0f, dot)), esqv[j]);
      unsigned int b = __float_as_uint(dist);
      unsigned int sb = (b & 0x80000000u) ? ~b : (b | 0x80000000u);
      u64 key = ((u64)sb << 32) | (unsigned)(klane + j);
      best = best < key ? best : key;
    }
#pragma unroll
    for (int off = 32; off > 0; off >>= 1) {
      u64 o = __shfl_xor((unsigned long long)best, off, 64);
      best = best < o ? best : o;
    }
    if (lane == 0) atomicMin(&slots[n0w + r], best);
  }
}

// ---------------------------------------------------------------------------
// Kernel 3: gather quantized rows (one wave per row), f32 outputs, loss
// partials into 256 hashed f64 buckets (no single-address CAS storm).
// ---------------------------------------------------------------------------
__global__ __launch_bounds__(256) void vq_out(
    const float* __restrict__ x, const float* __restrict__ e,
    const u64* __restrict__ slots, float* __restrict__ out_q,
    float* __restrict__ out_idx, double* __restrict__ loss_part) {
  const int t = threadIdx.x;
  const int w = t >> 6, lane = t & 63;
  const int n = blockIdx.x * 4 + w;
  const int idx = (int)(slots[n] & 0xFFFFFFFFULL);
  const float4* qr = (const float4*)(e + (size_t)idx * D_DIM);
  const float4* xr = (const float4*)(x + (size_t)n * D_DIM);
  float4* outr = (float4*)(out_q + (size_t)n * D_DIM);
  double s = 0.0;
#pragma unroll
  for (int i = 0; i < 2; ++i) {
    const int d4 = lane * 2 + i;  // 0..127
    float4 q = qr[d4];
    float4 xv = xr[d4];
    outr[d4] = q;
    double d0 = (double)xv.x - (double)q.x;
    double d1 = (double)xv.y - (double)q.y;
    double d2 = (double)xv.z - (double)q.z;
    double d3 = (double)xv.w - (double)q.w;
    s += d0 * d0 + d1 * d1 + d2 * d2 + d3 * d3;
  }
  for (int off = 32; off > 0; off >>= 1) s += __shfl_down(s, off, 64);
  if (lane == 0) {
    out_idx[n] = (float)idx;
    atomicAdd(&loss_part[(n * 37) & 255], s);
  }
}

__global__ void vq_loss(const double* __restrict__ loss_part,
                        float* __restrict__ out_s) {
  __shared__ double sm[256];
  const int t = threadIdx.x;
  sm[t] = loss_part[t];
  __syncthreads();
  for (int off = 128; off > 0; off >>= 1) {
    if (t < off) sm[t] += sm[t + off];
    __syncthreads();
  }
  if (t == 0) {
    double m = sm[0] / (double)(N_ROWS * D_DIM);
    out_s[0] = (float)(0.25 * m);
    out_s[1] = (float)m;
    out_s[2] = (float)(1.25 * m);
  }
}

extern "C" void kernel_launch(void* const* d_in, const int* in_sizes, int n_in,
                              void* d_out, int out_size, void* d_ws, size_t ws_size,
                              hipStream_t stream) {
  const float* x = (const float*)d_in[0];
  const float* emb = (const float*)d_in[1];
  float* out = (float*)d_out;

  // ws: [0,64K) u64 slots; [64K,96K) f32 x_sq; [96K,128K) f32 e_sq;
  //     [128K,130K) f64 loss_part[256]
  u64* slots = (u64*)d_ws;
  float* x_sq = (float*)((char*)d_ws + 65536);
  float* e_sq = (float*)((char*)d_ws + 98304);
  double* loss_part = (double*)((char*)d_ws + 131072);

  hipMemsetAsync(d_ws, 0xFF, 65536, stream);
  hipMemsetAsync(loss_part, 0, 256 * sizeof(double), stream);

  vq_sq<<<(2 * N_ROWS) / 256, 256, 0, stream>>>(x, emb, x_sq, e_sq);
  vq_dist<<<8192, 256, 0, stream>>>(x, emb, x_sq, e_sq, slots);
  vq_out<<<N_ROWS / 4, 256, 0, stream>>>(x, emb, slots, out,
                                         out + N_ROWS * D_DIM, loss_part);
  vq_loss<<<1, 256, 0, stream>>>(loss_part, out + N_ROWS * D_DIM + N_ROWS);
}

// Round 5
// 1046.659 us; speedup vs baseline: 1.8047x; 1.1262x over previous
//
#include <hip/hip_runtime.h>

#define N_ROWS 8192
#define K_CODES 8192
#define D_DIM 512

typedef unsigned long long u64;

// ---------------------------------------------------------------------------
// numpy pairwise summation of squares (bit-exact, unchanged from passing R3/R4).
// ---------------------------------------------------------------------------
__device__ __forceinline__ float pw_base128_sq(const float* __restrict__ p) {
  float r0 = __fmul_rn(p[0], p[0]);
  float r1 = __fmul_rn(p[1], p[1]);
  float r2 = __fmul_rn(p[2], p[2]);
  float r3 = __fmul_rn(p[3], p[3]);
  float r4 = __fmul_rn(p[4], p[4]);
  float r5 = __fmul_rn(p[5], p[5]);
  float r6 = __fmul_rn(p[6], p[6]);
  float r7 = __fmul_rn(p[7], p[7]);
  for (int i = 8; i < 128; i += 8) {
    r0 = __fadd_rn(r0, __fmul_rn(p[i + 0], p[i + 0]));
    r1 = __fadd_rn(r1, __fmul_rn(p[i + 1], p[i + 1]));
    r2 = __fadd_rn(r2, __fmul_rn(p[i + 2], p[i + 2]));
    r3 = __fadd_rn(r3, __fmul_rn(p[i + 3], p[i + 3]));
    r4 = __fadd_rn(r4, __fmul_rn(p[i + 4], p[i + 4]));
    r5 = __fadd_rn(r5, __fmul_rn(p[i + 5], p[i + 5]));
    r6 = __fadd_rn(r6, __fmul_rn(p[i + 6], p[i + 6]));
    r7 = __fadd_rn(r7, __fmul_rn(p[i + 7], p[i + 7]));
  }
  return __fadd_rn(__fadd_rn(__fadd_rn(r0, r1), __fadd_rn(r2, r3)),
                   __fadd_rn(__fadd_rn(r4, r5), __fadd_rn(r6, r7)));
}

__device__ __forceinline__ float pw_sq_512(const float* __restrict__ p) {
  float b0 = pw_base128_sq(p);
  float b1 = pw_base128_sq(p + 128);
  float b2 = pw_base128_sq(p + 256);
  float b3 = pw_base128_sq(p + 384);
  return __fadd_rn(__fadd_rn(b0, b1), __fadd_rn(b2, b3));
}

__global__ __launch_bounds__(256) void vq_sq(const float* __restrict__ x,
                                             const float* __restrict__ emb,
                                             float* __restrict__ x_sq,
                                             float* __restrict__ e_sq) {
  const int tid = blockIdx.x * 256 + threadIdx.x;
  if (tid < N_ROWS) {
    x_sq[tid] = pw_sq_512(x + tid * D_DIM);
  } else {
    const int k = tid - N_ROWS;
    e_sq[k] = pw_sq_512(emb + k * D_DIM);
  }
}

// ---------------------------------------------------------------------------
// Kernel 2: distance + argmin. Tile 64n x 256k per block (8 waves, 512 thr).
// Double-buffered LDS (2 x 32 KB), global_load_lds staging issued BEFORE
// compute of the current buffer (T3 2-phase pipeline), one vmcnt(0)+barrier
// per 32-dd chunk. No local arrays -> no scratch. FMA chain per output is
// bit-identical to the R3/R4-passing kernel (ascending dd, split at 384).
// LDS layout: 256 k-rows x 32 dd, quad-XOR swizzle: value for logical
// dd-quad q of row k lives at phys quad q ^ ((k>>3)&7).
// ---------------------------------------------------------------------------
__device__ __forceinline__ void compute_chunk(const float* __restrict__ esb,
                                              const float* __restrict__ xw,
                                              int dd0, int lane,
                                              float (&acc)[8][4]) {
  const int ebase = lane * 128;
  const int lm = (lane >> 1) & 7;  // ((4*lane+j)>>3)&7, j<4
#pragma unroll
  for (int g = 0; g < 8; ++g) {
    const float* p = esb + ebase + 4 * (g ^ lm);
    const float4 ev0 = *reinterpret_cast<const float4*>(p);
    const float4 ev1 = *reinterpret_cast<const float4*>(p + 32);
    const float4 ev2 = *reinterpret_cast<const float4*>(p + 64);
    const float4 ev3 = *reinterpret_cast<const float4*>(p + 96);
#pragma unroll
    for (int r = 0; r < 8; ++r) {
      const float4 xv =
          *reinterpret_cast<const float4*>(xw + r * D_DIM + dd0 + 4 * g);
      float a0 = acc[r][0], a1 = acc[r][1], a2 = acc[r][2], a3 = acc[r][3];
      a0 = __fmaf_rn(xv.x, ev0.x, a0);
      a0 = __fmaf_rn(xv.y, ev0.y, a0);
      a0 = __fmaf_rn(xv.z, ev0.z, a0);
      a0 = __fmaf_rn(xv.w, ev0.w, a0);
      a1 = __fmaf_rn(xv.x, ev1.x, a1);
      a1 = __fmaf_rn(xv.y, ev1.y, a1);
      a1 = __fmaf_rn(xv.z, ev1.z, a1);
      a1 = __fmaf_rn(xv.w, ev1.w, a1);
      a2 = __fmaf_rn(xv.x, ev2.x, a2);
      a2 = __fmaf_rn(xv.y, ev2.y, a2);
      a2 = __fmaf_rn(xv.z, ev2.z, a2);
      a2 = __fmaf_rn(xv.w, ev2.w, a2);
      a3 = __fmaf_rn(xv.x, ev3.x, a3);
      a3 = __fmaf_rn(xv.y, ev3.y, a3);
      a3 = __fmaf_rn(xv.z, ev3.z, a3);
      a3 = __fmaf_rn(xv.w, ev3.w, a3);
      acc[r][0] = a0; acc[r][1] = a1; acc[r][2] = a2; acc[r][3] = a3;
    }
  }
}

// One global_load_lds: lane t stages 16 B. LDS float idx 4t+2048*I (linear,
// = wave-uniform base + lane*16 B); global source pre-swizzled by sq4.
#define STAGE1(BUF, DD0, I)                                                    \
  __builtin_amdgcn_global_load_lds(                                            \
      (const __attribute__((address_space(1))) void*)(                         \
          e + (size_t)(k0 + (t >> 3) + 64 * (I)) * D_DIM + (DD0) + sq4),       \
      (__attribute__((address_space(3))) void*)(&es[BUF][4 * t + 2048 * (I)]), \
      16, 0, 0)
#define STAGE(BUF, DD0)                                                        \
  do {                                                                         \
    STAGE1(BUF, DD0, 0);                                                       \
    STAGE1(BUF, DD0, 1);                                                       \
    STAGE1(BUF, DD0, 2);                                                       \
    STAGE1(BUF, DD0, 3);                                                       \
  } while (0)

__global__ __launch_bounds__(512, 4) void vq_dist(
    const float* __restrict__ x, const float* __restrict__ e,
    const float* __restrict__ x_sq, const float* __restrict__ e_sq,
    u64* __restrict__ slots) {
  __shared__ float es[2][8192];  // 2 x 32 KB

  const int t = threadIdx.x;
  const int lane = t & 63;

  // XCD-aware bijective swizzle: 4096 blocks -> 512/XCD; one XCD works
  // through 128 consecutive n-blocks of the same k-panel (512 KB, L2-hot).
  const int bx = blockIdx.x;
  const int swz = (bx & 7) * 512 + (bx >> 3);
  const int kb = swz >> 7;    // 0..31
  const int nb = swz & 127;   // 0..127
  const int k0 = kb * 256;
  const int n0w = __builtin_amdgcn_readfirstlane(nb * 64 + (t >> 6) * 8);
  const float* xw = x + (size_t)n0w * D_DIM;

  // Stage source dd-quad: phys quad (t&7) XOR'd with k-row term ((t>>6)&7)
  // (i-independent in this geometry).
  const int sq4 = 4 * ((t & 7) ^ ((t >> 6) & 7));

  float accA[8][4], accB[8][4];
#pragma unroll
  for (int r = 0; r < 8; ++r)
#pragma unroll
    for (int j = 0; j < 4; ++j) { accA[r][j] = 0.0f; accB[r][j] = 0.0f; }

  // Prologue: fill buffer 0 with chunk 0.
  STAGE(0, 0);
  asm volatile("s_waitcnt vmcnt(0)" ::: "memory");
  __syncthreads();

  // Phase A: chunks 0..11 (dd < 384).
#pragma unroll 1
  for (int c = 0; c < 12; ++c) {
    STAGE((c + 1) & 1, (c + 1) * 32);
    compute_chunk(&es[c & 1][0], xw, c * 32, lane, accA);
    asm volatile("s_waitcnt vmcnt(0)" ::: "memory");
    __syncthreads();
  }
  // Phase B: chunks 12..15 (dd >= 384).
#pragma unroll 1
  for (int c = 12; c < 16; ++c) {
    if (c < 15) STAGE((c + 1) & 1, (c + 1) * 32);
    compute_chunk(&es[c & 1][0], xw, c * 32, lane, accB);
    asm volatile("s_waitcnt vmcnt(0)" ::: "memory");
    __syncthreads();
  }

  // Epilogue: dist = fl(fl(x_sq - 2*dot) + e_sq); packed-key argmin.
  const float4 xsqa = *reinterpret_cast<const float4*>(x_sq + n0w);
  const float4 xsqb = *reinterpret_cast<const float4*>(x_sq + n0w + 4);
  const float xsq[8] = {xsqa.x, xsqa.y, xsqa.z, xsqa.w,
                        xsqb.x, xsqb.y, xsqb.z, xsqb.w};
  const int klane = k0 + lane * 4;
  const float4 esq = *reinterpret_cast<const float4*>(e_sq + klane);
  const float esqv[4] = {esq.x, esq.y, esq.z, esq.w};

#pragma unroll
  for (int r = 0; r < 8; ++r) {
    u64 best = ~0ULL;
#pragma unroll
    for (int j = 0; j < 4; ++j) {
      float dot = __fadd_rn(accA[r][j], accB[r][j]);
      float dist = __fadd_rn(__fsub_rn(xsq[r], __fmul_rn(2.0f, dot)), esqv[j]);
      unsigned int b = __float_as_uint(dist);
      unsigned int sb = (b & 0x80000000u) ? ~b : (b | 0x80000000u);
      u64 key = ((u64)sb << 32) | (unsigned)(klane + j);
      best = best < key ? best : key;
    }
#pragma unroll
    for (int off = 32; off > 0; off >>= 1) {
      u64 o = __shfl_xor((unsigned long long)best, off, 64);
      best = best < o ? best : o;
    }
    if (lane == 0) atomicMin(&slots[n0w + r], best);
  }
}

// ---------------------------------------------------------------------------
// Kernel 3: gather quantized rows (one wave per row), f32 outputs, loss
// partials into 256 hashed f64 buckets.
// ---------------------------------------------------------------------------
__global__ __launch_bounds__(256) void vq_out(
    const float* __restrict__ x, const float* __restrict__ e,
    const u64* __restrict__ slots, float* __restrict__ out_q,
    float* __restrict__ out_idx, double* __restrict__ loss_part) {
  const int t = threadIdx.x;
  const int w = t >> 6, lane = t & 63;
  const int n = blockIdx.x * 4 + w;
  const int idx = (int)(slots[n] & 0xFFFFFFFFULL);
  const float4* qr = (const float4*)(e + (size_t)idx * D_DIM);
  const float4* xr = (const float4*)(x + (size_t)n * D_DIM);
  float4* outr = (float4*)(out_q + (size_t)n * D_DIM);
  double s = 0.0;
#pragma unroll
  for (int i = 0; i < 2; ++i) {
    const int d4 = lane * 2 + i;
    float4 q = qr[d4];
    float4 xv = xr[d4];
    outr[d4] = q;
    double d0 = (double)xv.x - (double)q.x;
    double d1 = (double)xv.y - (double)q.y;
    double d2 = (double)xv.z - (double)q.z;
    double d3 = (double)xv.w - (double)q.w;
    s += d0 * d0 + d1 * d1 + d2 * d2 + d3 * d3;
  }
  for (int off = 32; off > 0; off >>= 1) s += __shfl_down(s, off, 64);
  if (lane == 0) {
    out_idx[n] = (float)idx;
    atomicAdd(&loss_part[(n * 37) & 255], s);
  }
}

__global__ void vq_loss(const double* __restrict__ loss_part,
                        float* __restrict__ out_s) {
  __shared__ double sm[256];
  const int t = threadIdx.x;
  sm[t] = loss_part[t];
  __syncthreads();
  for (int off = 128; off > 0; off >>= 1) {
    if (t < off) sm[t] += sm[t + off];
    __syncthreads();
  }
  if (t == 0) {
    double m = sm[0] / (double)(N_ROWS * D_DIM);
    out_s[0] = (float)(0.25 * m);
    out_s[1] = (float)m;
    out_s[2] = (float)(1.25 * m);
  }
}

extern "C" void kernel_launch(void* const* d_in, const int* in_sizes, int n_in,
                              void* d_out, int out_size, void* d_ws, size_t ws_size,
                              hipStream_t stream) {
  const float* x = (const float*)d_in[0];
  const float* emb = (const float*)d_in[1];
  float* out = (float*)d_out;

  // ws: [0,64K) u64 slots; [64K,96K) f32 x_sq; [96K,128K) f32 e_sq;
  //     [128K,130K) f64 loss_part[256]
  u64* slots = (u64*)d_ws;
  float* x_sq = (float*)((char*)d_ws + 65536);
  float* e_sq = (float*)((char*)d_ws + 98304);
  double* loss_part = (double*)((char*)d_ws + 131072);

  hipMemsetAsync(d_ws, 0xFF, 65536, stream);
  hipMemsetAsync(loss_part, 0, 256 * sizeof(double), stream);

  vq_sq<<<(2 * N_ROWS) / 256, 256, 0, stream>>>(x, emb, x_sq, e_sq);
  vq_dist<<<4096, 512, 0, stream>>>(x, emb, x_sq, e_sq, slots);
  vq_out<<<N_ROWS / 4, 256, 0, stream>>>(x, emb, slots, out,
                                         out + N_ROWS * D_DIM, loss_part);
  vq_loss<<<1, 256, 0, stream>>>(loss_part, out + N_ROWS * D_DIM + N_ROWS);
}